// Round 4
// baseline (92.658 us; speedup 1.0000x reference)
//
#include <hip/hip_runtime.h>

#define GTCR_EPS 0.001f
#define GTCR_D 4096

// Fused single kernel: 2048 blocks x 256 threads; one row per WAVE (4/block).
// Row = 1024 float4; each lane reads 16 float4 (lane + 64k) => full coverage,
// 16 independent loads in flight. Wave shuffle-reduce -> log1p on lane 0,
// block LDS-sum, one atomicAdd per block, last block writes the output.
__global__ __launch_bounds__(256) void gtcr_fused_kernel(
    const float* __restrict__ z, float* __restrict__ out,
    float* __restrict__ acc, unsigned int* __restrict__ ctr,
    float lmbd, int nblocks, float inv_B) {
    const int wid  = threadIdx.x >> 6;   // wave 0..3
    const int lane = threadIdx.x & 63;
    const int row  = blockIdx.x * 4 + wid;

    const float4* zr = reinterpret_cast<const float4*>(z) + (size_t)row * (GTCR_D / 4);

    float s0 = 0.0f, s1 = 0.0f, s2 = 0.0f, s3 = 0.0f;
    #pragma unroll
    for (int k = 0; k < 16; k += 4) {
        float4 v0 = zr[lane + 64 * (k + 0)];
        float4 v1 = zr[lane + 64 * (k + 1)];
        float4 v2 = zr[lane + 64 * (k + 2)];
        float4 v3 = zr[lane + 64 * (k + 3)];
        s0 = fmaf(v0.x, v0.x, fmaf(v0.y, v0.y, fmaf(v0.z, v0.z, fmaf(v0.w, v0.w, s0))));
        s1 = fmaf(v1.x, v1.x, fmaf(v1.y, v1.y, fmaf(v1.z, v1.z, fmaf(v1.w, v1.w, s1))));
        s2 = fmaf(v2.x, v2.x, fmaf(v2.y, v2.y, fmaf(v2.z, v2.z, fmaf(v2.w, v2.w, s2))));
        s3 = fmaf(v3.x, v3.x, fmaf(v3.y, v3.y, fmaf(v3.z, v3.z, fmaf(v3.w, v3.w, s3))));
    }
    float s = (s0 + s1) + (s2 + s3);

    // Wave-64 shuffle reduction: full row sum lands in lane 0.
    #pragma unroll
    for (int off = 32; off > 0; off >>= 1)
        s += __shfl_down(s, off, 64);

    __shared__ float wres[4];
    if (lane == 0) wres[wid] = log1pf(lmbd * s);
    __syncthreads();

    if (threadIdx.x == 0) {
        float bsum = (wres[0] + wres[1]) + (wres[2] + wres[3]);
        atomicAdd(acc, bsum);            // device-scope RMW
        __threadfence();                 // release: acc add visible before ctr bump
        unsigned int old = atomicAdd(ctr, 1u);
        if (old == (unsigned int)(nblocks - 1)) {
            __threadfence();             // acquire side (belt & suspenders)
            float total = atomicAdd(acc, 0.0f);  // coherent RMW read
            out[0] = -0.5f * total * inv_B;
        }
    }
}

extern "C" void kernel_launch(void* const* d_in, const int* in_sizes, int n_in,
                              void* d_out, int out_size, void* d_ws, size_t ws_size,
                              hipStream_t stream) {
    const float* z = (const float*)d_in[0];
    float* out = (float*)d_out;

    const int B = in_sizes[0] / GTCR_D;          // 8192
    const int nblocks = B / 4;                   // 2048 = 8 blocks/CU exactly
    const float lmbd = (float)GTCR_D * ((float)B * GTCR_EPS);  // 33554.432

    float* acc = (float*)d_ws;                               // offset 0
    unsigned int* ctr = (unsigned int*)((char*)d_ws + 64);   // separate cache line

    hipMemsetAsync(d_ws, 0, 128, stream);        // zero acc + ctr each call
    gtcr_fused_kernel<<<nblocks, 256, 0, stream>>>(
        z, out, acc, ctr, lmbd, nblocks, 1.0f / (float)B);
}

// Round 5
// 27.301 us; speedup vs baseline: 3.3939x; 3.3939x over previous
//
#include <hip/hip_runtime.h>

#define GTCR_EPS 0.001f
#define GTCR_D 4096

// Kernel 1: 2048 blocks x 256 threads; one row per WAVE (4 rows/block).
// Row = 1024 float4; lane reads 16 float4 (lane + 64k) => full coverage.
// Wave shuffle-reduce -> log1p on lane 0, block sums 4 waves in LDS,
// ONE plain store per block (no atomics). partial[block] = sum of 4 log1p.
__global__ __launch_bounds__(256) void gtcr_row_kernel(
    const float* __restrict__ z, float* __restrict__ partial, float lmbd) {
    const int wid  = threadIdx.x >> 6;   // wave 0..3
    const int lane = threadIdx.x & 63;
    const int row  = blockIdx.x * 4 + wid;

    const float4* zr = reinterpret_cast<const float4*>(z) + (size_t)row * (GTCR_D / 4);

    float s0 = 0.0f, s1 = 0.0f, s2 = 0.0f, s3 = 0.0f;
    #pragma unroll
    for (int k = 0; k < 16; k += 4) {
        float4 v0 = zr[lane + 64 * (k + 0)];
        float4 v1 = zr[lane + 64 * (k + 1)];
        float4 v2 = zr[lane + 64 * (k + 2)];
        float4 v3 = zr[lane + 64 * (k + 3)];
        s0 = fmaf(v0.x, v0.x, fmaf(v0.y, v0.y, fmaf(v0.z, v0.z, fmaf(v0.w, v0.w, s0))));
        s1 = fmaf(v1.x, v1.x, fmaf(v1.y, v1.y, fmaf(v1.z, v1.z, fmaf(v1.w, v1.w, s1))));
        s2 = fmaf(v2.x, v2.x, fmaf(v2.y, v2.y, fmaf(v2.z, v2.z, fmaf(v2.w, v2.w, s2))));
        s3 = fmaf(v3.x, v3.x, fmaf(v3.y, v3.y, fmaf(v3.z, v3.z, fmaf(v3.w, v3.w, s3))));
    }
    float s = (s0 + s1) + (s2 + s3);

    // Wave-64 shuffle reduction: full row sum lands in lane 0.
    #pragma unroll
    for (int off = 32; off > 0; off >>= 1)
        s += __shfl_down(s, off, 64);

    __shared__ float wres[4];
    if (lane == 0) wres[wid] = log1pf(lmbd * s);
    __syncthreads();

    if (threadIdx.x == 0)
        partial[blockIdx.x] = (wres[0] + wres[1]) + (wres[2] + wres[3]);
}

// Kernel 2: single block reduces 2048 partials (8 KB, one coalesced pass).
__global__ __launch_bounds__(256) void gtcr_final_kernel(
    const float* __restrict__ partial, float* __restrict__ out, float scale) {
    const float4* p4 = reinterpret_cast<const float4*>(partial);
    float4 a = p4[threadIdx.x];          // 512 float4 total: 2 per thread
    float4 b = p4[threadIdx.x + 256];
    float s = ((a.x + a.y) + (a.z + a.w)) + ((b.x + b.y) + (b.z + b.w));

    #pragma unroll
    for (int off = 32; off > 0; off >>= 1)
        s += __shfl_down(s, off, 64);

    __shared__ float wsum[4];
    const int lane = threadIdx.x & 63;
    const int wid  = threadIdx.x >> 6;
    if (lane == 0) wsum[wid] = s;
    __syncthreads();
    if (threadIdx.x == 0) {
        float t = (wsum[0] + wsum[1]) + (wsum[2] + wsum[3]);
        out[0] = scale * t;   // scale = -0.5 / B
    }
}

extern "C" void kernel_launch(void* const* d_in, const int* in_sizes, int n_in,
                              void* d_out, int out_size, void* d_ws, size_t ws_size,
                              hipStream_t stream) {
    const float* z = (const float*)d_in[0];
    float* out = (float*)d_out;
    float* partial = (float*)d_ws;               // 2048 floats, fully overwritten

    const int B = in_sizes[0] / GTCR_D;          // 8192
    const int nblocks = B / 4;                   // 2048 = 8 blocks/CU exactly
    const float lmbd = (float)GTCR_D * ((float)B * GTCR_EPS);  // 33554.432

    gtcr_row_kernel<<<nblocks, 256, 0, stream>>>(z, partial, lmbd);
    gtcr_final_kernel<<<1, 256, 0, stream>>>(partial, out, -0.5f / (float)B);
}